// Round 3
// baseline (795.468 us; speedup 1.0000x reference)
//
#include <hip/hip_runtime.h>
#include <hip/hip_bf16.h>

#define Bn 64
#define Kn 24
#define Nn 934
#define NBLK 4            // gram blocks per batch
#define CHUNK 234         // ceil(934/4)
#define GW 160            // padded G width (154 cols + rhs col at 154)

// ws layout: double G[Bn][GW][GW]
#define G_ELEMS ((size_t)Bn * GW * GW)

// ---------------- Stage 1: fp64 Gram accumulation ---------------------------
__global__ __launch_bounds__(1024) void k_gram(
    const float* __restrict__ uv, const float* __restrict__ xm,
    const float* __restrict__ bs, const float* __restrict__ blend,
    const float* __restrict__ Wp, const float* __restrict__ m00,
    const float* __restrict__ m11, const float* __restrict__ m02,
    const float* __restrict__ m12, double* __restrict__ Gd)
{
    __shared__ float part[4][8][30];
    __shared__ float sm[8][30];
    __shared__ float rows[8][2][GW];

    const int tid = threadIdx.x;
    const int b = blockIdx.y;
    const int n0 = blockIdx.x * CHUNK;
    const int nEnd = min(n0 + CHUNK, Nn);
    const float f0 = m00[b], f1 = m11[b], cx = m02[b], cy = m12[b];

    // zero pad cols 155..159 once
    if (tid < 80) {
        const int p = tid / 10, rem = tid % 10, h = rem / 5, c = 155 + rem % 5;
        rows[p][h][c] = 0.0f;
    }

    double acc[5][5];
    #pragma unroll
    for (int i = 0; i < 5; ++i)
        #pragma unroll
        for (int j = 0; j < 5; ++j) acc[i][j] = 0.0;

    const int ti = tid >> 5, tj = tid & 31;   // 32x32 grid
    const int NR = (CHUNK + 7) / 8;           // 30
    __syncthreads();

    for (int rd = 0; rd < NR; ++rd) {
        const int nb = n0 + rd * 8;
        // ---- A: bs partial K-sums (4 k-groups of 6) ----
        if (tid < 960) {
            const int k4 = tid / 240, rem = tid % 240;
            const int p = rem / 30, cj = rem % 30;
            const int n = nb + p;
            float a = 0.0f;
            if (n < nEnd) {
                const float* bp = bs + ((size_t)(b * Kn + k4 * 6) * Nn + n) * 30 + cj;
                #pragma unroll
                for (int m = 0; m < 6; ++m) a += bp[(size_t)m * Nn * 30];
            }
            part[k4][p][cj] = a;
        }
        __syncthreads();
        // ---- B: sm finalize; rotation/translation cols; b col ----
        if (tid < 240) {
            const int p = tid / 30, cj = tid % 30;
            sm[p][cj] = part[0][p][cj] + part[1][p][cj] + part[2][p][cj] + part[3][p][cj];
        } else if (tid >= 256 && tid < 448) {
            const int i = tid - 256;
            const int k = i >> 3, p = i & 7;
            const int n = nb + p;
            float* rx = &rows[p][0][k * 6];
            float* ry = &rows[p][1][k * 6];
            if (n < nEnd) {
                const float* xp = xm + ((size_t)(b * Kn + k) * Nn + n) * 3;
                const float x0 = xp[0], x1 = xp[1], x2 = xp[2];
                const float bl = blend[n * Kn + k];
                const float u = uv[((size_t)b * Nn + n) * 2 + 0];
                const float v = uv[((size_t)b * Nn + n) * 2 + 1];
                const float dxu = cx - u, dyv = cy - v;
                const float w = Wp[(size_t)b * Nn + n];
                rx[0] = w * dxu * x1;
                rx[1] = w * (f0 * x2 - dxu * x0);
                rx[2] = -w * f0 * x1;
                rx[3] = w * bl * f0;
                rx[4] = 0.0f;
                rx[5] = w * bl * dxu;
                ry[0] = w * (dyv * x1 - f1 * x2);
                ry[1] = -w * dyv * x0;
                ry[2] = w * f1 * x0;
                ry[3] = 0.0f;
                ry[4] = w * bl * f1;
                ry[5] = w * bl * dyv;
            } else {
                #pragma unroll
                for (int e = 0; e < 6; ++e) { rx[e] = 0.0f; ry[e] = 0.0f; }
            }
        } else if (tid >= 448 && tid < 464) {
            const int i = tid - 448;
            const int p = i >> 1, h = i & 1;
            const int n = nb + p;
            float val = 0.0f;
            if (n < nEnd) {
                float s0 = 0.0f, s1 = 0.0f, s2 = 0.0f;
                const float* xp = xm + ((size_t)b * Kn * Nn + n) * 3;
                #pragma unroll
                for (int k = 0; k < Kn; ++k) {
                    s0 += xp[(size_t)k * Nn * 3 + 0];
                    s1 += xp[(size_t)k * Nn * 3 + 1];
                    s2 += xp[(size_t)k * Nn * 3 + 2];
                }
                const float u = uv[((size_t)b * Nn + n) * 2 + 0];
                const float v = uv[((size_t)b * Nn + n) * 2 + 1];
                const float w = Wp[(size_t)b * Nn + n];
                val = h ? w * (-f1 * s1 - (cy - v) * s2)
                        : w * (-f0 * s0 - (cx - u) * s2);
            }
            rows[p][h][154] = val;
        }
        __syncthreads();
        // ---- C: shape cols ----
        if (tid < 160) {
            const int p = tid / 20, rem = tid % 20, h = rem / 10, e = rem % 10;
            const int n = nb + p;
            float val = 0.0f;
            if (n < nEnd) {
                const float u = uv[((size_t)b * Nn + n) * 2 + 0];
                const float v = uv[((size_t)b * Nn + n) * 2 + 1];
                const float w = Wp[(size_t)b * Nn + n];
                val = h ? w * (f1 * sm[p][10 + e] + (cy - v) * sm[p][20 + e])
                        : w * (f0 * sm[p][e]      + (cx - u) * sm[p][20 + e]);
            }
            rows[p][h][144 + e] = val;
        }
        __syncthreads();
        // ---- D: fp64 rank-16 Gram update (5x5 tiles) ----
        #pragma unroll
        for (int p = 0; p < 8; ++p) {
            #pragma unroll
            for (int h = 0; h < 2; ++h) {
                double rv[5], rh[5];
                #pragma unroll
                for (int i = 0; i < 5; ++i) rv[i] = (double)rows[p][h][ti * 5 + i];
                #pragma unroll
                for (int j = 0; j < 5; ++j) rh[j] = (double)rows[p][h][tj * 5 + j];
                #pragma unroll
                for (int i = 0; i < 5; ++i)
                    #pragma unroll
                    for (int j = 0; j < 5; ++j)
                        acc[i][j] = fma(rv[i], rh[j], acc[i][j]);
            }
        }
        // next A writes part[] only; rows[] rewritten after the A-sync.
    }

    double* Gb = Gd + (size_t)b * GW * GW;
    #pragma unroll
    for (int i = 0; i < 5; ++i) {
        const int gi = ti * 5 + i;
        #pragma unroll
        for (int j = 0; j < 5; ++j) {
            const int gj = tj * 5 + j;
            if (gi < 155 && gj < 155)
                unsafeAtomicAdd(&Gb[(size_t)gi * GW + gj], acc[i][j]);
        }
    }
}

// ---------------- Stage 2: fp64 LDL^T solve + outputs (float32) ------------
__global__ __launch_bounds__(256) void k_solve(
    const float* __restrict__ pbeta, const float* __restrict__ vR,
    const double* __restrict__ Gd, float* __restrict__ out)
{
    __shared__ double tri[11935];   // lower triangle of 154x154, 95.5 KB
    __shared__ double cv[154];
    __shared__ double dinv[154];

    const int tid = threadIdx.x;
    const int b = blockIdx.x;
    const double lam2 = 1.0 / 9.0;
    const double* Gb = Gd + (size_t)b * GW * GW;

    // load lower triangle
    for (int idx = tid; idx < 11935; idx += 256) {
        // row from triangular index
        int i = (int)((sqrtf(8.0f * (float)idx + 1.0f) - 1.0f) * 0.5f);
        while (((i + 1) * (i + 2)) / 2 <= idx) ++i;
        while ((i * (i + 1)) / 2 > idx) --i;
        const int j = idx - (i * (i + 1)) / 2;
        double g = Gb[(size_t)i * GW + j];
        if (i == j && i >= 144) g += lam2;
        tri[idx] = g;
    }
    if (tid < 154) {
        double c0 = Gb[(size_t)tid * GW + 154];
        if (tid >= 144) c0 += lam2 * (double)pbeta[b * 10 + (tid - 144)];
        cv[tid] = c0;
    }
    __syncthreads();

    // LDL^T, raw columns
    const int ty = tid >> 4, tx = tid & 15;
    for (int j = 0; j < 153; ++j) {
        const double invd = 1.0 / tri[((j * (j + 1)) >> 1) + j];
        for (int ii = j + 1 + ty; ii < 154; ii += 16) {
            const int bi = (ii * (ii + 1)) >> 1;
            const double mij = tri[bi + j] * invd;
            for (int kk = j + 1 + tx; kk <= ii; kk += 16)
                tri[bi + kk] -= mij * tri[((kk * (kk + 1)) >> 1) + j];
        }
        __syncthreads();
    }
    if (tid < 154) dinv[tid] = 1.0 / tri[((tid * (tid + 1)) >> 1) + tid];
    __syncthreads();
    // scale to unit lower L
    for (int i = ty; i < 154; i += 16) {
        const int bi = (i * (i + 1)) >> 1;
        for (int j = tx; j < i; j += 16) tri[bi + j] *= dinv[j];
    }
    __syncthreads();
    // forward: L y = c
    for (int j = 0; j < 153; ++j) {
        const double yj = cv[j];
        for (int i = j + 1 + tid; i < 154; i += 256)
            cv[i] -= tri[((i * (i + 1)) >> 1) + j] * yj;
        __syncthreads();
    }
    if (tid < 154) cv[tid] *= dinv[tid];
    __syncthreads();
    // backward: L^T x = y
    for (int j = 153; j > 0; --j) {
        const double xj = cv[j];
        const int bj = (j * (j + 1)) >> 1;
        for (int i = tid; i < j; i += 256) cv[i] -= tri[bj + i] * xj;
        __syncthreads();
    }
    __syncthreads();

    // epilogue: Rodrigues + outputs (float32)
    if (tid < Kn) {
        const int k = tid;
        const double rxv = cv[6 * k + 0], ryv = cv[6 * k + 1], rzv = cv[6 * k + 2];
        const double t0 = cv[6 * k + 3], t1 = cv[6 * k + 4], t2 = cv[6 * k + 5];
        const double nrm = sqrt(rxv * rxv + ryv * ryv + rzv * rzv);
        const double th = fmax(nrm, 1e-8);
        const double ax = rxv / th, ay = ryv / th, az = rzv / th;
        const double c = cos(th), sn = sin(th), mc = 1.0 - c;
        double R[3][3];
        R[0][0] = c + mc * ax * ax;        R[0][1] = -sn * az + mc * ax * ay; R[0][2] =  sn * ay + mc * ax * az;
        R[1][0] =  sn * az + mc * ay * ax; R[1][1] = c + mc * ay * ay;        R[1][2] = -sn * ax + mc * ay * az;
        R[2][0] = -sn * ay + mc * az * ax; R[2][1] =  sn * ax + mc * az * ay; R[2][2] = c + mc * az * az;

        const float* VRp = vR + ((size_t)(b * Kn + k)) * 16;
        float* oc = out + ((size_t)(b * Kn + k)) * 16;
        #pragma unroll
        for (int r = 0; r < 3; ++r)
            #pragma unroll
            for (int cc = 0; cc < 4; ++cc) {
                const double val = R[r][0] * (double)VRp[0 * 4 + cc]
                                 + R[r][1] * (double)VRp[1 * 4 + cc]
                                 + R[r][2] * (double)VRp[2 * 4 + cc];
                oc[r * 4 + cc] = (float)val;
            }
        #pragma unroll
        for (int cc = 0; cc < 4; ++cc) oc[12 + cc] = VRp[12 + cc];

        float* ot = out + 24576 + ((size_t)(b * Kn + k)) * 3;
        ot[0] = (float)t0;
        ot[1] = (float)t1;
        ot[2] = (float)t2;

        float* orp = out + 29824 + ((size_t)(b * Kn + k)) * 9;
        #pragma unroll
        for (int r = 0; r < 3; ++r)
            #pragma unroll
            for (int cc = 0; cc < 3; ++cc)
                orp[r * 3 + cc] = (float)R[r][cc];
    }
    if (tid >= 32 && tid < 42) {
        out[29184 + b * 10 + (tid - 32)] = (float)cv[144 + (tid - 32)];
    }
}

extern "C" void kernel_launch(void* const* d_in, const int* in_sizes, int n_in,
                              void* d_out, int out_size, void* d_ws, size_t ws_size,
                              hipStream_t stream) {
    const float* uv    = (const float*)d_in[0];
    const float* xm    = (const float*)d_in[1];
    const float* bs    = (const float*)d_in[2];
    const float* blend = (const float*)d_in[3];
    const float* Wp    = (const float*)d_in[4];
    const float* m00   = (const float*)d_in[5];
    const float* m11   = (const float*)d_in[6];
    const float* m02   = (const float*)d_in[7];
    const float* m12   = (const float*)d_in[8];
    const float* pbeta = (const float*)d_in[9];
    const float* vRp   = (const float*)d_in[10];
    float* out = (float*)d_out;
    double* Gd = (double*)d_ws;

    hipMemsetAsync(d_ws, 0, G_ELEMS * sizeof(double), stream);

    dim3 gG(NBLK, Bn);
    k_gram<<<gG, 1024, 0, stream>>>(uv, xm, bs, blend, Wp, m00, m11, m02, m12, Gd);
    k_solve<<<Bn, 256, 0, stream>>>(pbeta, vRp, Gd, out);
}

// Round 4
// 554.293 us; speedup vs baseline: 1.4351x; 1.4351x over previous
//
#include <hip/hip_runtime.h>
#include <hip/hip_bf16.h>

#define Bn 64
#define Kn 24
#define Nn 934
#define NBLK 4
#define GCH 234          // points per gram block
#define RNDS 15          // 15 * 16 = 240 >= 234
#define GPK 12090        // 155*156/2 packed lower (row 154 = rhs row)

// ws layout: [0, 6190080) fp64 packed G ; then fp32 pre[Bn][Nn][22]
#define G_BYTES ((size_t)Bn * GPK * 8)

// ---------------- k_pre: stream-reduce b_s_ and xm over K -------------------
// pre[b][n][0..9]=sxcol, [10..19]=sycol, [20]=bx, [21]=by  (all include W)
__global__ __launch_bounds__(1024) void k_pre(
    const float* __restrict__ uv, const float* __restrict__ xm,
    const float* __restrict__ bs, const float* __restrict__ Wp,
    const float* __restrict__ m00, const float* __restrict__ m11,
    const float* __restrict__ m02, const float* __restrict__ m12,
    float* __restrict__ pre)
{
    __shared__ float smL[32][30];
    __shared__ float xsL[32][3];
    const int tid = threadIdx.x;
    const int b = blockIdx.y;
    const int n0 = blockIdx.x * 32;
    const float f0 = m00[b], f1 = m11[b], cx = m02[b], cy = m12[b];

    if (tid < 960) {
        const int ni = tid / 30, c = tid - ni * 30;
        const int nc = min(n0 + ni, Nn - 1);
        float acc = 0.0f;
        const float* bp = bs + ((size_t)(b * Kn) * Nn + nc) * 30 + c;
        #pragma unroll
        for (int k = 0; k < Kn; ++k) acc += bp[(size_t)k * Nn * 30];
        smL[ni][c] = acc;
    } else {
        const int v = tid - 960;
        #pragma unroll
        for (int rep = 0; rep < 2; ++rep) {
            const int w = v + rep * 64;
            if (w < 96) {
                const int ni = w / 3, c = w - ni * 3;
                const int nc = min(n0 + ni, Nn - 1);
                float acc = 0.0f;
                const float* xp = xm + ((size_t)(b * Kn) * Nn + nc) * 3 + c;
                #pragma unroll
                for (int k = 0; k < Kn; ++k) acc += xp[(size_t)k * Nn * 3];
                xsL[ni][c] = acc;
            }
        }
    }
    __syncthreads();

    if (tid < 704) {
        const int ni = tid / 22, e = tid - ni * 22;
        const int n = n0 + ni;
        if (n < Nn) {
            const float u = uv[((size_t)b * Nn + n) * 2 + 0];
            const float v = uv[((size_t)b * Nn + n) * 2 + 1];
            const float w = Wp[(size_t)b * Nn + n];
            const float dxu = cx - u, dyv = cy - v;
            float val;
            if (e < 10)       val = w * (f0 * smL[ni][e] + dxu * smL[ni][20 + e]);
            else if (e < 20)  val = w * (f1 * smL[ni][e] + dyv * smL[ni][e + 10]);
            else if (e == 20) val = w * (-f0 * xsL[ni][0] - dxu * xsL[ni][2]);
            else              val = w * (-f1 * xsL[ni][1] - dyv * xsL[ni][2]);
            pre[((size_t)b * Nn + n) * 22 + e] = val;
        }
    }
}

// ---------------- k_gram: dbuf rows + lower-tri fp64 Gram -------------------
__global__ __launch_bounds__(1024) void k_gram(
    const float* __restrict__ uv, const float* __restrict__ xm,
    const float* __restrict__ blend, const float* __restrict__ Wp,
    const float* __restrict__ m00, const float* __restrict__ m11,
    const float* __restrict__ m02, const float* __restrict__ m12,
    const float* __restrict__ pre, double* __restrict__ Gpk)
{
    __shared__ float rows[2][16][2][160];   // 80 KB
    const int tid = threadIdx.x;
    const int b = blockIdx.y;
    const int n0 = blockIdx.x * GCH;
    const int nEnd = min(n0 + GCH, Nn);
    const float f0 = m00[b], f1 = m11[b], cx = m02[b], cy = m12[b];

    const bool isB = tid < 384;
    const int bk = tid >> 4, bp = tid & 15;
    const bool isP = (tid >= 384) && (tid < 736);
    const int q = tid - 384;
    const int pp = q / 22, pe = q - pp * 22;

    int ti = 0, tj = 0;
    if (tid < 496) {
        int t = tid;
        int row = (int)((sqrtf(8.0f * (float)t + 1.0f) - 1.0f) * 0.5f);
        while ((row + 1) * (row + 2) / 2 <= t) ++row;
        while (row * (row + 1) / 2 > t) --row;
        ti = row; tj = t - row * (row + 1) / 2;
    }

    double acc[5][5] = {};
    float pf_x0 = 0, pf_x1 = 0, pf_x2 = 0, pf_bl = 0, pf_u = 0, pf_v = 0, pf_w = 0, pf_pre = 0;

    auto PREFETCH = [&](int rnd) {
        const int nb = n0 + rnd * 16;
        if (isB) {
            const int n = min(nb + bp, Nn - 1);
            const float* xp = xm + ((size_t)(b * Kn + bk) * Nn + n) * 3;
            pf_x0 = xp[0]; pf_x1 = xp[1]; pf_x2 = xp[2];
            pf_bl = blend[n * Kn + bk];
            pf_u = uv[((size_t)b * Nn + n) * 2 + 0];
            pf_v = uv[((size_t)b * Nn + n) * 2 + 1];
            pf_w = Wp[(size_t)b * Nn + n];
        } else if (isP) {
            const int n = min(nb + pp, Nn - 1);
            pf_pre = pre[((size_t)b * Nn + n) * 22 + pe];
        }
    };
    auto BUILD = [&](int rnd, int bufi) {
        const int nb = n0 + rnd * 16;
        if (isB) {
            const int n = nb + bp;
            float* rx = &rows[bufi][bp][0][bk * 6];
            float* ry = &rows[bufi][bp][1][bk * 6];
            if (n < nEnd) {
                const float dxu = cx - pf_u, dyv = cy - pf_v, w = pf_w;
                const float wbl = w * pf_bl;
                rx[0] = w * dxu * pf_x1;
                rx[1] = w * (f0 * pf_x2 - dxu * pf_x0);
                rx[2] = -w * f0 * pf_x1;
                rx[3] = wbl * f0;
                rx[4] = 0.0f;
                rx[5] = wbl * dxu;
                ry[0] = w * (dyv * pf_x1 - f1 * pf_x2);
                ry[1] = -w * dyv * pf_x0;
                ry[2] = w * f1 * pf_x0;
                ry[3] = 0.0f;
                ry[4] = wbl * f1;
                ry[5] = wbl * dyv;
            } else {
                #pragma unroll
                for (int e = 0; e < 6; ++e) { rx[e] = 0.0f; ry[e] = 0.0f; }
            }
        } else if (isP) {
            const int n = nb + pp;
            const float v = (n < nEnd) ? pf_pre : 0.0f;
            if (pe < 10)       rows[bufi][pp][0][144 + pe] = v;
            else if (pe < 20)  rows[bufi][pp][1][134 + pe] = v;
            else if (pe == 20) rows[bufi][pp][0][154] = v;
            else               rows[bufi][pp][1][154] = v;
        }
    };

    // zero pad cols 155..159 of both buffers (never rewritten)
    if (tid < 320) {
        const int bufi = tid / 160, rem = tid - bufi * 160;
        const int p = rem / 10, h = (rem % 10) / 5, c = 155 + rem % 5;
        rows[bufi][p][h][c] = 0.0f;
    }

    PREFETCH(0);
    BUILD(0, 0);
    PREFETCH(1);
    __syncthreads();

    for (int r = 0; r < RNDS; ++r) {
        const int cur = r & 1, nxt = cur ^ 1;
        if (r < RNDS - 1) {
            BUILD(r + 1, nxt);
            if (r < RNDS - 2) PREFETCH(r + 2);
        }
        if (tid < 496) {
            for (int p = 0; p < 16; ++p) {
                #pragma unroll
                for (int h = 0; h < 2; ++h) {
                    const float* rr = &rows[cur][p][h][0];
                    double rv[5], rh[5];
                    #pragma unroll
                    for (int i = 0; i < 5; ++i) rv[i] = (double)rr[ti * 5 + i];
                    #pragma unroll
                    for (int j = 0; j < 5; ++j) rh[j] = (double)rr[tj * 5 + j];
                    #pragma unroll
                    for (int i = 0; i < 5; ++i)
                        #pragma unroll
                        for (int j = 0; j < 5; ++j)
                            acc[i][j] = fma(rv[i], rh[j], acc[i][j]);
                }
            }
        }
        __syncthreads();
    }

    double* Gb = Gpk + (size_t)b * GPK;
    if (tid < 496) {
        #pragma unroll
        for (int i = 0; i < 5; ++i) {
            const int gi = ti * 5 + i;
            const int base = (gi * (gi + 1)) >> 1;
            #pragma unroll
            for (int j = 0; j < 5; ++j) {
                const int gj = tj * 5 + j;
                if (gj <= gi) unsafeAtomicAdd(&Gb[base + gj], acc[i][j]);
            }
        }
    }
}

// ---------------- k_solve: LDL^T + wave-sync substitution + outputs ---------
__global__ __launch_bounds__(256) void k_solve(
    const float* __restrict__ pbeta, const float* __restrict__ vR,
    const double* __restrict__ Gpk, float* __restrict__ out)
{
    __shared__ double tri[11935];
    __shared__ double cv[160];
    __shared__ double dinv[154];
    const int tid = threadIdx.x;
    const int b = blockIdx.x;
    const double lam2 = 1.0 / 9.0;
    const double* Gb = Gpk + (size_t)b * GPK;

    for (int idx = tid; idx < 11935; idx += 256) tri[idx] = Gb[idx];
    if (tid < 154) {
        double c0 = Gb[11935 + tid];
        if (tid >= 144) c0 += lam2 * (double)pbeta[b * 10 + (tid - 144)];
        cv[tid] = c0;
    }
    __syncthreads();
    if (tid < 10) {
        const int d = 144 + tid;
        tri[((d * (d + 1)) >> 1) + d] += lam2;
    }
    __syncthreads();

    // LDL^T (raw columns kept; dinv folded into substitution)
    const int ty = tid >> 4, tx = tid & 15;
    for (int j = 0; j < 153; ++j) {
        const double invd = 1.0 / tri[((j * (j + 1)) >> 1) + j];
        for (int ii = j + 1 + ty; ii < 154; ii += 16) {
            const int bi = (ii * (ii + 1)) >> 1;
            const double mij = tri[bi + j] * invd;
            int kk = j + 1 + tx;
            int bk2 = (kk * (kk + 1)) >> 1;
            while (kk <= ii) {
                tri[bi + kk] -= mij * tri[bk2 + j];
                bk2 += (kk << 4) + 136;
                kk += 16;
            }
        }
        __syncthreads();
    }
    if (tid < 154) dinv[tid] = 1.0 / tri[((tid * (tid + 1)) >> 1) + tid];
    __syncthreads();

    // forward + D-scale (single wave, no barriers): cv becomes w = D^-1 L^-1 c
    if (tid < 64) {
        for (int j = 0; j < 154; ++j) {
            const double wj = cv[j] * dinv[j];
            cv[j] = wj;
            for (int i = j + 1 + tid; i < 154; i += 64)
                cv[i] -= tri[((i * (i + 1)) >> 1) + j] * wj;
        }
        // backward: x[i] = w[i] - dinv[i] * sum_j R[j][i] x[j]
        for (int j = 153; j >= 1; --j) {
            const double xj = cv[j];
            const int bj = (j * (j + 1)) >> 1;
            for (int i = tid; i < j; i += 64)
                cv[i] -= dinv[i] * tri[bj + i] * xj;
        }
    }

    // epilogue (wave 0 only — same wave that finished bwd, no barrier needed)
    if (tid < Kn) {
        const int k = tid;
        const double rxv = cv[6 * k + 0], ryv = cv[6 * k + 1], rzv = cv[6 * k + 2];
        const double t0 = cv[6 * k + 3], t1 = cv[6 * k + 4], t2 = cv[6 * k + 5];
        const double nrm = sqrt(rxv * rxv + ryv * ryv + rzv * rzv);
        const double th = fmax(nrm, 1e-8);
        const double ax = rxv / th, ay = ryv / th, az = rzv / th;
        const double c = cos(th), sn = sin(th), mc = 1.0 - c;
        double R[3][3];
        R[0][0] = c + mc * ax * ax;        R[0][1] = -sn * az + mc * ax * ay; R[0][2] =  sn * ay + mc * ax * az;
        R[1][0] =  sn * az + mc * ay * ax; R[1][1] = c + mc * ay * ay;        R[1][2] = -sn * ax + mc * ay * az;
        R[2][0] = -sn * ay + mc * az * ax; R[2][1] =  sn * ax + mc * az * ay; R[2][2] = c + mc * az * az;

        const float* VRp = vR + ((size_t)(b * Kn + k)) * 16;
        float* oc = out + ((size_t)(b * Kn + k)) * 16;
        #pragma unroll
        for (int r = 0; r < 3; ++r)
            #pragma unroll
            for (int cc = 0; cc < 4; ++cc) {
                const double val = R[r][0] * (double)VRp[0 * 4 + cc]
                                 + R[r][1] * (double)VRp[1 * 4 + cc]
                                 + R[r][2] * (double)VRp[2 * 4 + cc];
                oc[r * 4 + cc] = (float)val;
            }
        #pragma unroll
        for (int cc = 0; cc < 4; ++cc) oc[12 + cc] = VRp[12 + cc];

        float* ot = out + 24576 + ((size_t)(b * Kn + k)) * 3;
        ot[0] = (float)t0; ot[1] = (float)t1; ot[2] = (float)t2;

        float* orp = out + 29824 + ((size_t)(b * Kn + k)) * 9;
        #pragma unroll
        for (int r = 0; r < 3; ++r)
            #pragma unroll
            for (int cc = 0; cc < 3; ++cc)
                orp[r * 3 + cc] = (float)R[r][cc];
    }
    if (tid >= 32 && tid < 42) {
        out[29184 + b * 10 + (tid - 32)] = (float)cv[144 + (tid - 32)];
    }
}

extern "C" void kernel_launch(void* const* d_in, const int* in_sizes, int n_in,
                              void* d_out, int out_size, void* d_ws, size_t ws_size,
                              hipStream_t stream) {
    const float* uv    = (const float*)d_in[0];
    const float* xm    = (const float*)d_in[1];
    const float* bs    = (const float*)d_in[2];
    const float* blend = (const float*)d_in[3];
    const float* Wp    = (const float*)d_in[4];
    const float* m00   = (const float*)d_in[5];
    const float* m11   = (const float*)d_in[6];
    const float* m02   = (const float*)d_in[7];
    const float* m12   = (const float*)d_in[8];
    const float* pbeta = (const float*)d_in[9];
    const float* vRp   = (const float*)d_in[10];
    float* out = (float*)d_out;
    double* Gpk = (double*)d_ws;
    float* pre = (float*)((char*)d_ws + G_BYTES);

    hipMemsetAsync(d_ws, 0, G_BYTES, stream);

    dim3 gP((Nn + 31) / 32, Bn);
    k_pre<<<gP, 1024, 0, stream>>>(uv, xm, bs, Wp, m00, m11, m02, m12, pre);

    dim3 gG(NBLK, Bn);
    k_gram<<<gG, 1024, 0, stream>>>(uv, xm, blend, Wp, m00, m11, m02, m12, pre, Gpk);

    k_solve<<<Bn, 256, 0, stream>>>(pbeta, vRp, Gpk, out);
}